// Round 4
// baseline (243.924 us; speedup 1.0000x reference)
//
#include <hip/hip_runtime.h>
#include <stdint.h>

// NVFP4Linear: M=128 (8x16), K=I=8192, N=O=8192
// d_in[0] hidden: f32 [128][8192]  (reference fp16 promoted to f32 by harness)
// d_in[1] weight: int32[8192][4096], one packed byte per int (low nibble = even k)
// d_in[2] weight_scale: f32 [8192][512] (per 16-k group)
// d_in[3] weight_scale_2: f32[1] ; d_in[4] input_scale: f32[1]
// d_out: f32 [128][8192]

typedef _Float16 half8 __attribute__((ext_vector_type(8)));
typedef float float4v __attribute__((ext_vector_type(4)));

__device__ __forceinline__ uint32_t perm_b32(uint32_t hi, uint32_t lo, uint32_t sel) {
  return __builtin_amdgcn_perm(hi, lo, sel);
}

// Async global->LDS DMA, 16B per lane. LDS dest must be the WAVE-UNIFORM base;
// HW adds lane*16. Global src is per-lane.
__device__ __forceinline__ void load_lds16(const uint4* g, uint4* l) {
  __builtin_amdgcn_global_load_lds((const __attribute__((address_space(1))) void*)g,
                                   (__attribute__((address_space(3))) void*)l,
                                   16, 0, 0);
}

// RNE round-trip through fp8 e4m3fn (x >= 0, finite)
__device__ __forceinline__ float e4m3_roundtrip(float x) {
  if (x < 0.015625f) {               // subnormal region: grid step 2^-9
    return __builtin_rintf(x * 512.0f) * 0.001953125f;
  }
  uint32_t u = __float_as_uint(x);
  u += 0x7FFFFu + ((u >> 20) & 1u);  // RNE to 3 mantissa bits
  u &= 0xFFF00000u;
  float y = __uint_as_float(u);
  return fminf(y, 448.0f);
}

// ---------------- Kernel 1: activation QDQ -> swizzled f16 A fragments ----------------
// A_sw fragment (kb, mb) = 64 lanes x 16B; lane l holds A[mb*16 + (l&15)][kb*32 + (l>>4)*8 + j]
__global__ __launch_bounds__(256)
void aqdq_kernel(const float* __restrict__ hs,
                 const float* __restrict__ isc,
                 uint2* __restrict__ asw) {
  const int t = blockIdx.x * 256 + threadIdx.x;   // 262144 total
  const int m = t >> 11;                          // row 0..127
  const int u = t & 2047;
  const int g = u >> 2;                           // group within row 0..511
  const int hq = u & 3;                           // quarter of group

  const float* p = hs + m * 8192 + g * 16 + hq * 4;
  float4 x = *(const float4*)p;

  float amax = fmaxf(fmaxf(fabsf(x.x), fabsf(x.y)), fmaxf(fabsf(x.z), fabsf(x.w)));
  amax = fmaxf(amax, __shfl_xor(amax, 1));
  amax = fmaxf(amax, __shfl_xor(amax, 2));

  float is = isc[0];
  float s = e4m3_roundtrip(amax / (6.0f * is));
  if (!(s > 0.0f)) s = 1.0f;
  float total = s * is;

  float xv[4] = {x.x, x.y, x.z, x.w};
  union { _Float16 h[4]; uint2 v; } qq;
#pragma unroll
  for (int i = 0; i < 4; ++i) {
    float r = xv[i] / total;         // correctly-rounded f32 div, matches jnp
    float a = fabsf(r);
    // E2M1 nearest; ties -> lower magnitude (searchsorted side='left')
    float v = (a <= 0.25f) ? 0.0f
            : (a <= 0.75f) ? 0.5f
            : (a <= 1.25f) ? 1.0f
            : (a <= 1.75f) ? 1.5f
            : (a <= 2.5f)  ? 2.0f
            : (a <= 3.5f)  ? 3.0f
            : (a <= 5.0f)  ? 4.0f : 6.0f;
    qq.h[i] = (_Float16)(copysignf(v, r) * total);  // exact in f16
  }

  const int k = g * 16 + hq * 4;
  const int kb = k >> 5;
  const int quad = (k >> 3) & 3;
  const int lane16 = (m & 15) | (quad << 4);
  const int mb = m >> 4;
  asw[((kb * 8 + mb) * 64 + lane16) * 2 + (hq & 1)] = qq.v;
}

// ---------------- fp4 pair decode: 4 packed bytes (8 codes) -> 8 scaled f16 ----------------
__device__ __forceinline__ half8 decode_scale(int4 w, float sf) {
  uint32_t t0 = perm_b32((uint32_t)w.y, (uint32_t)w.x, 0x00000400u);
  uint32_t t1 = perm_b32((uint32_t)w.w, (uint32_t)w.z, 0x04000000u);
  uint32_t b  = perm_b32(t1, t0, 0x07060100u); // byte i = codes (k2i, k2i+1)
  uint32_t ev = b & 0x0F0F0F0Fu;               // even-k nibbles
  uint32_t od = (b >> 4) & 0x0F0F0F0Fu;        // odd-k nibbles
  uint32_t evm = ev & 0x07070707u;
  uint32_t odm = od & 0x07070707u;
  uint32_t evs = (ev & 0x08080808u) << 4;      // sign -> byte-high bit (f16 bit15)
  uint32_t ods = (od & 0x08080808u) << 4;
  // f16 high bytes of {0,.5,1,1.5,2,3,4,6} = {00,38,3C,3E,40,42,44,46}
  uint32_t evh = perm_b32(0x46444240u, 0x3E3C3800u, evm) | evs;
  uint32_t odh = perm_b32(0x46444240u, 0x3E3C3800u, odm) | ods;
  union { uint32_t u[4]; half8 h; } r;
  r.u[0] = perm_b32(odh, evh, 0x04000000u) & 0xFF00FF00u; // (k1,k0)
  r.u[1] = perm_b32(odh, evh, 0x05000100u) & 0xFF00FF00u; // (k3,k2)
  r.u[2] = perm_b32(odh, evh, 0x06000200u) & 0xFF00FF00u; // (k5,k4)
  r.u[3] = perm_b32(odh, evh, 0x07000300u) & 0xFF00FF00u; // (k7,k6)
  _Float16 hsf = (_Float16)sf;
  half8 sv = {hsf, hsf, hsf, hsf, hsf, hsf, hsf, hsf};
  return r.h * sv;                              // v_pk_mul_f16 x4
}

// ---------------- Kernel 2: cooperative fused dequant GEMM, distance-2 pipeline ----------------
// Grid 512 = 64 n-blocks x 8 k-parts (kp = bid&7 -> per-XCD A-slice L2 locality).
// Block: 8 waves on the same k range; wave wv owns cols [nb*128+wv*16, +16), all 128 m.
// Per 32-k step t: issue {A-DMA(t+2) via global_load_lds, weight int4(t+2), scale(t+2)}
// (exactly 3 VMEM ops), s_waitcnt vmcnt(6) (keeps t+1/t+2 in flight ACROSS the barrier),
// raw s_barrier, then 8 ds_read_b128 + decode + 8 MFMAs.
// Safety: 4 LDS buffers + distance 2 => DMA(t+2) issued after barrier(t-1), by which all
// waves' reads of that buffer (step t-2) have retired; vmcnt(6) before barrier(t) covers
// this wave's own A(t) DMA. (ledger in session notes)
template<int MODE>
__global__ __launch_bounds__(512, 4)
void gemm_kernel(const uint4* __restrict__ asw,
                 const int* __restrict__ wq,
                 const float* __restrict__ wsc,
                 const float* __restrict__ ws2p,
                 float* __restrict__ dst) {
  __shared__ uint4 abuf[4][8][64];    // 32 KiB, 4-deep A k-slice ring (frag layout)
  const int lane = threadIdx.x & 63;
  const int wv = threadIdx.x >> 6;    // wave 0..7 = n-subtile
  const int quad = lane >> 4;
  const int kp = blockIdx.x & 7;      // k-part (== XCD id for bid round-robin)
  const int nb = blockIdx.x >> 3;     // n-tile 0..63
  const int col = nb * 128 + wv * 16 + (lane & 15);
  const float ws2 = ws2p[0];
  const int4* wp = (const int4*)(wq + (size_t)col * 4096) + kp * 128 + quad;
  const float2* sp = (const float2*)(wsc + (size_t)col * 512 + kp * 64);
  const uint4* ap = asw + kp * 16384 + wv * 64 + lane;  // frag (kb=kp*32+t, mb=wv), per-lane src

  float4v acc[8];
#pragma unroll
  for (int mb = 0; mb < 8; ++mb) acc[mb] = (float4v){0.f, 0.f, 0.f, 0.f};

  int4 wreg[4];
  float2 sreg[4];

  // ---- prologue: stage steps 0 and 1 (6 VMEM ops in flight) ----
  load_lds16(ap, &abuf[0][wv][0]);
  wreg[0] = wp[0];
  sreg[0] = sp[0];
  load_lds16(ap + 512, &abuf[1][wv][0]);
  wreg[1] = wp[4];
  sreg[1] = sp[1];

#define STEP_BODY(J, STAGE_EN, VMCNT_N)                                           \
  {                                                                               \
    if (STAGE_EN) {                                                               \
      load_lds16(apg + ((J) + 2) * 512, &abuf[((J) + 2) & 3][wv][0]);             \
      wreg[((J) + 2) & 3] = wpg[((J) + 2) * 4];                                   \
      sreg[((J) + 2) & 3] = spg[(J) + 2];                                         \
    }                                                                             \
    __builtin_amdgcn_sched_barrier(0);                                            \
    asm volatile("s_waitcnt vmcnt(" #VMCNT_N ")" ::: "memory");                   \
    __builtin_amdgcn_s_barrier();                                                 \
    __builtin_amdgcn_sched_barrier(0);                                            \
    uint4 af[8];                                                                  \
    _Pragma("unroll")                                                             \
    for (int mb = 0; mb < 8; ++mb) af[mb] = abuf[(J)][mb][lane];                  \
    float sA = ((quad & 2) ? sreg[(J)].y : sreg[(J)].x) * ws2;                    \
    half8 bA = decode_scale(wreg[(J)], sA);                                       \
    _Pragma("unroll")                                                             \
    for (int mb = 0; mb < 8; ++mb) {                                              \
      union { uint4 u; half8 h; } a;                                              \
      a.u = af[mb];                                                               \
      acc[mb] = __builtin_amdgcn_mfma_f32_16x16x32_f16(a.h, bA, acc[mb], 0, 0, 0);\
    }                                                                             \
  }

  {
    const uint4* apg = ap;
    const int4* wpg = wp;
    const float2* spg = sp;
    for (int tt = 0; tt < 28; tt += 4) {   // t = 0..27, all stage t+2 <= 29
      STEP_BODY(0, true, 6)
      STEP_BODY(1, true, 6)
      STEP_BODY(2, true, 6)
      STEP_BODY(3, true, 6)
      apg += 4 * 512;
      wpg += 16;
      spg += 4;
    }
    // peeled tail: t = 28..31 (bases now at t=28)
    STEP_BODY(0, true, 6)    // t=28 stages t=30 -> buf 2
    STEP_BODY(1, true, 6)    // t=29 stages t=31 -> buf 3
    STEP_BODY(2, false, 3)   // t=30: only t=31's 3 ops remain in flight
    STEP_BODY(3, false, 0)   // t=31: drain
  }
#undef STEP_BODY

  // Epilogue. C/D layout: n = lane&15, m = quad*4 + reg (verified m89/m91)
  if (MODE == 0) {
    float* pp = dst + ((size_t)kp << 20) + col;
#pragma unroll
    for (int mb = 0; mb < 8; ++mb) {
      const int mrow = mb * 16 + quad * 4;
#pragma unroll
      for (int r = 0; r < 4; ++r) pp[(size_t)(mrow + r) * 8192] = acc[mb][r];
    }
  } else {
#pragma unroll
    for (int mb = 0; mb < 8; ++mb) {
      const int mrow = mb * 16 + quad * 4;
#pragma unroll
      for (int r = 0; r < 4; ++r)
        unsafeAtomicAdd(&dst[(size_t)(mrow + r) * 8192 + col], acc[mb][r]);
    }
  }
}

// ---------------- Kernel 3: k-part reduction (MODE-0 path) ----------------
__global__ __launch_bounds__(256)
void reduce_kernel(const float4* __restrict__ part, float4* __restrict__ out) {
  const int i = blockIdx.x * 256 + threadIdx.x;   // 262144 float4 = 1M floats
  float4 s = part[i];
#pragma unroll
  for (int p = 1; p < 8; ++p) {
    float4 b = part[(size_t)p * 262144 + i];
    s.x += b.x; s.y += b.y; s.z += b.z; s.w += b.w;
  }
  out[i] = s;
}

extern "C" void kernel_launch(void* const* d_in, const int* in_sizes, int n_in,
                              void* d_out, int out_size, void* d_ws, size_t ws_size,
                              hipStream_t stream) {
  (void)in_sizes; (void)n_in; (void)out_size;
  const float* hs  = (const float*)d_in[0];   // f32 [128][8192]
  const int* wq    = (const int*)d_in[1];     // int32 [8192][4096]
  const float* wsc = (const float*)d_in[2];   // f32 [8192][512]
  const float* ws2 = (const float*)d_in[3];   // f32 [1]
  const float* isc = (const float*)d_in[4];   // f32 [1]
  float* out       = (float*)d_out;           // f32 [128][8192]
  uint2* asw2      = (uint2*)d_ws;            // 2 MiB swizzled f16 A fragments (8B store view)
  const uint4* asw4 = (const uint4*)d_ws;     // same buffer, 16B fragment view

  aqdq_kernel<<<1024, 256, 0, stream>>>(hs, isc, asw2);

  const size_t need = ((size_t)2 << 20) + ((size_t)32 << 20);  // asw + partials
  if (ws_size >= need) {
    float* part = (float*)((char*)d_ws + ((size_t)2 << 20));   // f32 [8][128][8192]
    gemm_kernel<0><<<512, 512, 0, stream>>>(asw4, wq, wsc, ws2, part);
    reduce_kernel<<<1024, 256, 0, stream>>>((const float4*)part, (float4*)out);
  } else {
    hipMemsetAsync(out, 0, (size_t)128 * 8192 * 4, stream);
    gemm_kernel<1><<<512, 512, 0, stream>>>(asw4, wq, wsc, ws2, out);
  }
}

// Round 5
// 241.520 us; speedup vs baseline: 1.0100x; 1.0100x over previous
//
#include <hip/hip_runtime.h>
#include <stdint.h>

// NVFP4Linear: M=128 (8x16), K=I=8192, N=O=8192
// d_in[0] hidden: f32 [128][8192]  (reference fp16 promoted to f32 by harness)
// d_in[1] weight: int32[8192][4096], one packed byte per int (low nibble = even k)
// d_in[2] weight_scale: f32 [8192][512] (per 16-k group)
// d_in[3] weight_scale_2: f32[1] ; d_in[4] input_scale: f32[1]
// d_out: f32 [128][8192]

typedef _Float16 half8 __attribute__((ext_vector_type(8)));
typedef float float4v __attribute__((ext_vector_type(4)));

__device__ __forceinline__ uint32_t perm_b32(uint32_t hi, uint32_t lo, uint32_t sel) {
  return __builtin_amdgcn_perm(hi, lo, sel);
}

// Async global->LDS DMA, 16B per lane. LDS dest must be the WAVE-UNIFORM base;
// HW adds lane*16. Global src is per-lane.
__device__ __forceinline__ void load_lds16(const uint4* g, uint4* l) {
  __builtin_amdgcn_global_load_lds((const __attribute__((address_space(1))) void*)g,
                                   (__attribute__((address_space(3))) void*)l,
                                   16, 0, 0);
}

// RNE round-trip through fp8 e4m3fn (x >= 0, finite)
__device__ __forceinline__ float e4m3_roundtrip(float x) {
  if (x < 0.015625f) {               // subnormal region: grid step 2^-9
    return __builtin_rintf(x * 512.0f) * 0.001953125f;
  }
  uint32_t u = __float_as_uint(x);
  u += 0x7FFFFu + ((u >> 20) & 1u);  // RNE to 3 mantissa bits
  u &= 0xFFF00000u;
  float y = __uint_as_float(u);
  return fminf(y, 448.0f);
}

// ---------------- Kernel 1: activation QDQ -> swizzled f16 A fragments ----------------
// A_sw fragment (kb, mb) = 64 lanes x 16B; lane l holds A[mb*16 + (l&15)][kb*32 + (l>>4)*8 + j]
__global__ __launch_bounds__(256)
void aqdq_kernel(const float* __restrict__ hs,
                 const float* __restrict__ isc,
                 uint2* __restrict__ asw) {
  const int t = blockIdx.x * 256 + threadIdx.x;   // 262144 total
  const int m = t >> 11;                          // row 0..127
  const int u = t & 2047;
  const int g = u >> 2;                           // group within row 0..511
  const int hq = u & 3;                           // quarter of group

  const float* p = hs + m * 8192 + g * 16 + hq * 4;
  float4 x = *(const float4*)p;

  float amax = fmaxf(fmaxf(fabsf(x.x), fabsf(x.y)), fmaxf(fabsf(x.z), fabsf(x.w)));
  amax = fmaxf(amax, __shfl_xor(amax, 1));
  amax = fmaxf(amax, __shfl_xor(amax, 2));

  float is = isc[0];
  float s = e4m3_roundtrip(amax / (6.0f * is));
  if (!(s > 0.0f)) s = 1.0f;
  float total = s * is;

  float xv[4] = {x.x, x.y, x.z, x.w};
  union { _Float16 h[4]; uint2 v; } qq;
#pragma unroll
  for (int i = 0; i < 4; ++i) {
    float r = xv[i] / total;         // correctly-rounded f32 div, matches jnp
    float a = fabsf(r);
    // E2M1 nearest; ties -> lower magnitude (searchsorted side='left')
    float v = (a <= 0.25f) ? 0.0f
            : (a <= 0.75f) ? 0.5f
            : (a <= 1.25f) ? 1.0f
            : (a <= 1.75f) ? 1.5f
            : (a <= 2.5f)  ? 2.0f
            : (a <= 3.5f)  ? 3.0f
            : (a <= 5.0f)  ? 4.0f : 6.0f;
    qq.h[i] = (_Float16)(copysignf(v, r) * total);  // exact in f16
  }

  const int k = g * 16 + hq * 4;
  const int kb = k >> 5;
  const int quad = (k >> 3) & 3;
  const int lane16 = (m & 15) | (quad << 4);
  const int mb = m >> 4;
  asw[((kb * 8 + mb) * 64 + lane16) * 2 + (hq & 1)] = qq.v;
}

// ---------------- fp4 decode: packed u32 (4 bytes = 8 codes) -> 8 scaled f16 ----------------
__device__ __forceinline__ half8 decode_u32(uint32_t b, float sf) {
  uint32_t ev = b & 0x0F0F0F0Fu;               // even-k nibbles
  uint32_t od = (b >> 4) & 0x0F0F0F0Fu;        // odd-k nibbles
  uint32_t evm = ev & 0x07070707u;
  uint32_t odm = od & 0x07070707u;
  uint32_t evs = (ev & 0x08080808u) << 4;      // sign -> byte-high bit (f16 bit15)
  uint32_t ods = (od & 0x08080808u) << 4;
  // f16 high bytes of {0,.5,1,1.5,2,3,4,6} = {00,38,3C,3E,40,42,44,46}
  uint32_t evh = perm_b32(0x46444240u, 0x3E3C3800u, evm) | evs;
  uint32_t odh = perm_b32(0x46444240u, 0x3E3C3800u, odm) | ods;
  union { uint32_t u[4]; half8 h; } r;
  r.u[0] = perm_b32(odh, evh, 0x04000000u) & 0xFF00FF00u; // (k1,k0)
  r.u[1] = perm_b32(odh, evh, 0x05000100u) & 0xFF00FF00u; // (k3,k2)
  r.u[2] = perm_b32(odh, evh, 0x06000200u) & 0xFF00FF00u; // (k5,k4)
  r.u[3] = perm_b32(odh, evh, 0x07000300u) & 0xFF00FF00u; // (k7,k6)
  _Float16 hsf = (_Float16)sf;
  half8 sv = {hsf, hsf, hsf, hsf, hsf, hsf, hsf, hsf};
  return r.h * sv;                              // v_pk_mul_f16 x4
}

// ---------------- Kernel 2: cooperative fused dequant GEMM, linear weight streaming ----------
// Grid 512 = 64 n-blocks x 8 k-parts. Block: 8 waves; wave wv owns cols [nb*128+wv*16,+16).
// WEIGHT PATH (the 128 MiB stream): per 512-k half, wave wv loads its 16 cols' slices as
// 16 x {64 lanes x dwordx4} = 16 FULLY-CONTIGUOUS 1 KiB reads (lane l holds the 4 payload
// bytes for (step s=l>>2, quad q=l&3) of that col). Extract bytes (3 v_perm) and write one
// u32/lane into the XOR-swizzled wtile; MFMA steps read 1 u32/lane (2-way banks = free).
// W loads are issued a full half ahead (>=14-step slack). Per-step vmcnt stream is only
// {A-DMA, scale}: steady vmcnt(4); vmcnt(20) at the 2 steps straddling the W1 batch.
// MODE 0: write f32 partials [kp][128][8192]; MODE 1: unsafeAtomicAdd fallback.
template<int MODE>
__global__ __launch_bounds__(512, 2)
void gemm_kernel(const uint4* __restrict__ asw,
                 const int* __restrict__ wq,
                 const float* __restrict__ wsc,
                 const float* __restrict__ ws2p,
                 float* __restrict__ dst) {
  __shared__ uint4 abuf[4][8][64];       // 32 KiB A ring (frag layout), distance-2 DMA
  __shared__ uint32_t wtile[2][8192];    // 2 x 32 KiB packed-weight half-tiles (swizzled)
  const int lane = threadIdx.x & 63;
  const int wv = threadIdx.x >> 6;       // wave 0..7 = col group
  const int quad = lane >> 4;
  const int kp = blockIdx.x & 7;         // k-part
  const int nb = blockIdx.x >> 3;        // n-tile 0..63
  const int col = nb * 128 + wv * 16 + (lane & 15);
  const float ws2 = ws2p[0];
  const float2* sp = (const float2*)(wsc + (size_t)col * 512 + kp * 64);
  const uint4* ap = asw + kp * 16384 + wv * 64 + lane;   // A frag (kb=kp*32+t, mb=wv)
  const int4* wbase = (const int4*)wq;
  const int scol0 = nb * 128 + wv * 16;  // staging col base for this wave
  const int ws_s = lane >> 2;            // staging: step within half
  const int ws_q = lane & 3;             // staging: quad

  float4v acc[8];
#pragma unroll
  for (int mb = 0; mb < 8; ++mb) acc[mb] = (float4v){0.f, 0.f, 0.f, 0.f};

  float2 sreg[4];
  int4 wst[16];

  // ---- prologue ----
  // W0 loads: 16 x 1KiB contiguous (int4 idx = col*1024 + kp*128 + half*64 + lane)
#pragma unroll
  for (int j = 0; j < 16; ++j)
    wst[j] = wbase[(scol0 + j) * 1024 + kp * 128 + lane];
  load_lds16(ap, &abuf[0][wv][0]);
  sreg[0] = sp[0];
  load_lds16(ap + 512, &abuf[1][wv][0]);
  sreg[1] = sp[1];
  __builtin_amdgcn_sched_barrier(0);
  asm volatile("s_waitcnt vmcnt(4)" ::: "memory");   // W0 done; A0,S0,A1,S1 in flight
  __builtin_amdgcn_sched_barrier(0);
  // extract W0 -> wtile[0]
#pragma unroll
  for (int j = 0; j < 16; ++j) {
    int4 w = wst[j];
    uint32_t p0 = perm_b32((uint32_t)w.y, (uint32_t)w.x, 0x00000400u);
    uint32_t p1 = perm_b32((uint32_t)w.w, (uint32_t)w.z, 0x00000400u);
    uint32_t b  = perm_b32(p1, p0, 0x05040100u);     // [x0,y0,z0,w0] = 4 payload bytes
    const int cl = wv * 16 + j;
    wtile[0][ws_s * 512 + (((cl * 4 + ws_q) ^ ((ws_s & 7) << 2)))] = b;
  }
  // issue W1 (consumed from t=16; forced complete at t=2 -> extracted then)
#pragma unroll
  for (int j = 0; j < 16; ++j)
    wst[j] = wbase[(scol0 + j) * 1024 + kp * 128 + 64 + lane];

#define STEP(T, VN, STG, X1)                                                      \
  {                                                                               \
    if (STG) {                                                                    \
      load_lds16(ap + ((T) + 2) * 512, &abuf[((T) + 2) & 3][wv][0]);              \
      sreg[((T) + 2) & 3] = sp[(T) + 2];                                          \
    }                                                                             \
    __builtin_amdgcn_sched_barrier(0);                                            \
    asm volatile("s_waitcnt vmcnt(" #VN ")" ::: "memory");                        \
    __builtin_amdgcn_s_barrier();                                                 \
    __builtin_amdgcn_sched_barrier(0);                                            \
    uint4 af[8];                                                                  \
    _Pragma("unroll")                                                             \
    for (int mb = 0; mb < 8; ++mb) af[mb] = abuf[(T) & 3][mb][lane];              \
    const int s_ = (T) & 15;                                                      \
    uint32_t wb_ = wtile[((T) >> 4) & 1]                                          \
        [s_ * 512 + ((((wv * 16 + (lane & 15)) * 4 + quad)) ^ ((s_ & 7) << 2))];  \
    float sA = ((quad & 2) ? sreg[(T) & 3].y : sreg[(T) & 3].x) * ws2;            \
    half8 bA = decode_u32(wb_, sA);                                               \
    _Pragma("unroll")                                                             \
    for (int mb = 0; mb < 8; ++mb) {                                              \
      union { uint4 u; half8 h; } a_;                                             \
      a_.u = af[mb];                                                              \
      acc[mb] = __builtin_amdgcn_mfma_f32_16x16x32_f16(a_.h, bA, acc[mb], 0, 0, 0);\
    }                                                                             \
    if (X1) {                                                                     \
      _Pragma("unroll")                                                           \
      for (int j = 0; j < 16; ++j) {                                              \
        int4 w = wst[j];                                                          \
        uint32_t p0 = perm_b32((uint32_t)w.y, (uint32_t)w.x, 0x00000400u);        \
        uint32_t p1 = perm_b32((uint32_t)w.w, (uint32_t)w.z, 0x00000400u);        \
        uint32_t b  = perm_b32(p1, p0, 0x05040100u);                              \
        const int cl = wv * 16 + j;                                               \
        wtile[1][ws_s * 512 + (((cl * 4 + ws_q) ^ ((ws_s & 7) << 2)))] = b;       \
      }                                                                           \
    }                                                                             \
  }

  STEP(0, 20, 1, 0)
  STEP(1, 20, 1, 0)
  STEP(2, 4, 1, 1)   // vmcnt(4) retires W1 (16 oldest); extract -> wtile[1]
  STEP(3, 4, 1, 0)
  STEP(4, 4, 1, 0)
  STEP(5, 4, 1, 0)
  STEP(6, 4, 1, 0)
  STEP(7, 4, 1, 0)
  STEP(8, 4, 1, 0)
  STEP(9, 4, 1, 0)
  STEP(10, 4, 1, 0)
  STEP(11, 4, 1, 0)
  STEP(12, 4, 1, 0)
  STEP(13, 4, 1, 0)
  STEP(14, 4, 1, 0)
  STEP(15, 4, 1, 0)
  STEP(16, 4, 1, 0)
  STEP(17, 4, 1, 0)
  STEP(18, 4, 1, 0)
  STEP(19, 4, 1, 0)
  STEP(20, 4, 1, 0)
  STEP(21, 4, 1, 0)
  STEP(22, 4, 1, 0)
  STEP(23, 4, 1, 0)
  STEP(24, 4, 1, 0)
  STEP(25, 4, 1, 0)
  STEP(26, 4, 1, 0)
  STEP(27, 4, 1, 0)
  STEP(28, 4, 1, 0)
  STEP(29, 4, 1, 0)
  STEP(30, 2, 0, 0)
  STEP(31, 0, 0, 0)
#undef STEP

  // Epilogue. C/D layout: n = lane&15, m = quad*4 + reg (verified m89/m91)
  if (MODE == 0) {
    float* pp = dst + ((size_t)kp << 20) + col;
#pragma unroll
    for (int mb = 0; mb < 8; ++mb) {
      const int mrow = mb * 16 + quad * 4;
#pragma unroll
      for (int r = 0; r < 4; ++r) pp[(size_t)(mrow + r) * 8192] = acc[mb][r];
    }
  } else {
#pragma unroll
    for (int mb = 0; mb < 8; ++mb) {
      const int mrow = mb * 16 + quad * 4;
#pragma unroll
      for (int r = 0; r < 4; ++r)
        unsafeAtomicAdd(&dst[(size_t)(mrow + r) * 8192 + col], acc[mb][r]);
    }
  }
}

// ---------------- Kernel 3: k-part reduction (MODE-0 path) ----------------
__global__ __launch_bounds__(256)
void reduce_kernel(const float4* __restrict__ part, float4* __restrict__ out) {
  const int i = blockIdx.x * 256 + threadIdx.x;   // 262144 float4 = 1M floats
  float4 s = part[i];
#pragma unroll
  for (int p = 1; p < 8; ++p) {
    float4 b = part[(size_t)p * 262144 + i];
    s.x += b.x; s.y += b.y; s.z += b.z; s.w += b.w;
  }
  out[i] = s;
}

extern "C" void kernel_launch(void* const* d_in, const int* in_sizes, int n_in,
                              void* d_out, int out_size, void* d_ws, size_t ws_size,
                              hipStream_t stream) {
  (void)in_sizes; (void)n_in; (void)out_size;
  const float* hs  = (const float*)d_in[0];   // f32 [128][8192]
  const int* wq    = (const int*)d_in[1];     // int32 [8192][4096]
  const float* wsc = (const float*)d_in[2];   // f32 [8192][512]
  const float* ws2 = (const float*)d_in[3];   // f32 [1]
  const float* isc = (const float*)d_in[4];   // f32 [1]
  float* out       = (float*)d_out;           // f32 [128][8192]
  uint2* asw2      = (uint2*)d_ws;            // 2 MiB swizzled f16 A fragments (8B store view)
  const uint4* asw4 = (const uint4*)d_ws;     // same buffer, 16B fragment view

  aqdq_kernel<<<1024, 256, 0, stream>>>(hs, isc, asw2);

  const size_t need = ((size_t)2 << 20) + ((size_t)32 << 20);  // asw + partials
  if (ws_size >= need) {
    float* part = (float*)((char*)d_ws + ((size_t)2 << 20));   // f32 [8][128][8192]
    gemm_kernel<0><<<512, 512, 0, stream>>>(asw4, wq, wsc, ws2, part);
    reduce_kernel<<<1024, 256, 0, stream>>>((const float4*)part, (float4*)out);
  } else {
    hipMemsetAsync(out, 0, (size_t)128 * 8192 * 4, stream);
    gemm_kernel<1><<<512, 512, 0, stream>>>(asw4, wq, wsc, ws2, out);
  }
}